// Round 11
// baseline (307.596 us; speedup 1.0000x reference)
//
#include <hip/hip_runtime.h>
#include <math.h>

#define BB 128
#define QQ 900
#define GG 80
#define CC 92
#define NCL 91

// ---------------- ws layout (bytes) ----------------
#define COST_OFF 0            // float[BB*GG*QQ]  36,864,000
#define LSE_OFF  36864000     // float[BB*QQ]
#define VIDX_OFF 37324800     // int[BB*GG]
#define NV_OFF   37365760     // int[BB]
#define DUM_OFF  37366272     // float[64] dummy sink (old MQ slot, known-safe)
#define ACC_OFF  37407232     // double[4]  [S_base, ce_adj, l1, giou]

// Fused front kernel v2: FOUR blocks per batch (grid BB*4, 256 thr), each
// block owns 225 queries (1 per thread) -> all 256 CUs busy (was 128).
//  wave 0: ballot-compaction of valid gts (redundant per block, same values)
//  each q-thread: lse (identical fp32 op order to R10) + CE base partial
//  each q-thread: fp32 cost column cost[b][k][q] for k = 0..n-1
__global__ __launch_bounds__(256) void front_kernel(const float* __restrict__ logits,
                                                    const float* __restrict__ pboxes,
                                                    const float* __restrict__ gboxes,
                                                    const int* __restrict__ glabels,
                                                    float* __restrict__ lse_g,
                                                    int* __restrict__ valid_idx,
                                                    int* __restrict__ nvalid,
                                                    float* __restrict__ cost,
                                                    double* __restrict__ acc) {
    __shared__ int svidx[GG];
    __shared__ int s_n;
    __shared__ int slab[GG];
    __shared__ float sgx0[GG], sgy0[GG], sgx1[GG], sgy1[GG], sgar[GG];
    __shared__ float sgcx[GG], sgcy[GG], sgcz[GG], sgcw[GG];
    int blk = blockIdx.x;
    int b = blk >> 2;
    int part = blk & 3;
    int tid = threadIdx.x;
    if (tid < 64) {
        int lane = tid;
        bool v0 = glabels[b * GG + lane] < NCL;
        bool v1 = (lane < GG - 64) ? (glabels[b * GG + 64 + lane] < NCL) : false;
        unsigned long long m0 = __ballot(v0);
        unsigned long long m1 = __ballot(v1);
        int c0 = __popcll(m0);
        unsigned long long lower = lane ? (~0ULL >> (64 - lane)) : 0ULL;
        if (v0) { int p = __popcll(m0 & lower); svidx[p] = lane; valid_idx[b * GG + p] = lane; }
        if (v1) { int p = c0 + __popcll(m1 & lower); svidx[p] = 64 + lane; valid_idx[b * GG + p] = 64 + lane; }
        if (lane == 0) { s_n = c0 + __popcll(m1); nvalid[b] = s_n; }
    }
    __syncthreads();
    int n = s_n;

    int q = part * 225 + tid;   // tid < 225 -> q in [part*225, part*225+224], max 899
    bool qok = tid < 225;

    // lse (92 floats = exactly 23 float4 per row; op order identical to R10)
    double local = 0.0;
    float lse_q = 0.f;
    if (qok) {
        const float4* row4 = (const float4*)(logits + ((size_t)(b * QQ) + q) * CC);
        float mx = -INFINITY;
        for (int c = 0; c < 23; ++c) {
            float4 x = row4[c];
            mx = fmaxf(mx, fmaxf(fmaxf(x.x, x.y), fmaxf(x.z, x.w)));
        }
        float ssum = 0.f;
        float e91 = 0.f;
        for (int c = 0; c < 23; ++c) {
            float4 x = row4[c];
            ssum += expf(x.x - mx) + expf(x.y - mx) + expf(x.z - mx) + expf(x.w - mx);
            if (c == 22) e91 = x.w;  // element 91
        }
        lse_q = mx + logf(ssum);
        lse_g[b * QQ + q] = lse_q;
        local = (double)lse_q - (double)e91;
    }
#pragma unroll
    for (int off = 32; off; off >>= 1) local += __shfl_down(local, off);
    if ((tid & 63) == 0) atomicAdd(&acc[0], local);

    // gt staging
    for (int k = tid; k < n; k += 256) {
        int g = svidx[k];
        slab[k] = glabels[b * GG + g];
        float4 gb = ((const float4*)gboxes)[b * GG + g];
        sgcx[k] = gb.x; sgcy[k] = gb.y; sgcz[k] = gb.z; sgcw[k] = gb.w;
        float gx0 = gb.x - 0.5f * gb.z, gy0 = gb.y - 0.5f * gb.w;
        float gx1 = gb.x + 0.5f * gb.z, gy1 = gb.y + 0.5f * gb.w;
        sgx0[k] = gx0; sgy0[k] = gy0; sgx1[k] = gx1; sgy1[k] = gy1;
        sgar[k] = (gx1 - gx0) * (gy1 - gy0);
    }
    __syncthreads();

    // cost (identical fp32 op order to R10)
    if (qok) {
        float4 pb = ((const float4*)pboxes)[b * QQ + q];
        float px0 = pb.x - 0.5f * pb.z, py0 = pb.y - 0.5f * pb.w;
        float px1 = pb.x + 0.5f * pb.z, py1 = pb.y + 0.5f * pb.w;
        float parea = (px1 - px0) * (py1 - py0);
        const float* lrow = logits + ((size_t)(b * QQ) + q) * CC;
        for (int k = 0; k < n; ++k) {
            float l1 = fabsf(pb.x - sgcx[k]) + fabsf(pb.y - sgcy[k]) +
                       fabsf(pb.z - sgcz[k]) + fabsf(pb.w - sgcw[k]);
            float ltx = fmaxf(px0, sgx0[k]), lty = fmaxf(py0, sgy0[k]);
            float rbx = fminf(px1, sgx1[k]), rby = fminf(py1, sgy1[k]);
            float iw = fmaxf(rbx - ltx, 0.f), ih = fmaxf(rby - lty, 0.f);
            float inter = iw * ih;
            float uni = parea + sgar[k] - inter;
            float iou = inter / uni;
            float cx0 = fminf(px0, sgx0[k]), cy0 = fminf(py0, sgy0[k]);
            float cx1 = fmaxf(px1, sgx1[k]), cy1 = fmaxf(py1, sgy1[k]);
            float cw = fmaxf(cx1 - cx0, 0.f), ch = fmaxf(cy1 - cy0, 0.f);
            float ac = cw * ch;
            float giou = iou - (ac - uni) / ac;
            float cls = lse_q - lrow[slab[k]];
            cost[((size_t)(b * GG + k)) * QQ + q] = 5.f * l1 + cls - 2.f * giou;
        }
    }
}

// Wave64 min-reduce via DPP (row_shr 1/2/4/8 + bcast15/31), result in lane 63.
__device__ __forceinline__ unsigned wave_min_u32(unsigned x) {
    unsigned t;
    t = (unsigned)__builtin_amdgcn_update_dpp((int)x, (int)x, 0x111, 0xF, 0xF, false); x = x < t ? x : t;
    t = (unsigned)__builtin_amdgcn_update_dpp((int)x, (int)x, 0x112, 0xF, 0xF, false); x = x < t ? x : t;
    t = (unsigned)__builtin_amdgcn_update_dpp((int)x, (int)x, 0x114, 0xF, 0xF, false); x = x < t ? x : t;
    t = (unsigned)__builtin_amdgcn_update_dpp((int)x, (int)x, 0x118, 0xF, 0xF, false); x = x < t ? x : t;
    t = (unsigned)__builtin_amdgcn_update_dpp((int)x, (int)x, 0x142, 0xF, 0xF, false); x = x < t ? x : t;
    t = (unsigned)__builtin_amdgcn_update_dpp((int)x, (int)x, 0x143, 0xF, 0xF, false); x = x < t ? x : t;
    return (unsigned)__builtin_amdgcn_readlane((int)x, 63);
}
// fp32 variant (fminf; values here are never NaN).
__device__ __forceinline__ float wave_min_f32(float x) {
    float t;
#define MSTEP(ctrl)                                                                               \
    t = __uint_as_float((unsigned)__builtin_amdgcn_update_dpp(                                    \
        (int)__float_as_uint(x), (int)__float_as_uint(x), ctrl, 0xF, 0xF, false));                \
    x = fminf(x, t);
    MSTEP(0x111) MSTEP(0x112) MSTEP(0x114) MSTEP(0x118) MSTEP(0x142) MSTEP(0x143)
#undef MSTEP
    return __uint_as_float((unsigned)__builtin_amdgcn_readlane((int)__float_as_uint(x), 63));
}

// Exact rectangular LSA, one 64-lane wave per batch, v=0 init, rows 0..n-1
// (scipy traversal -- matching is traversal-determined, R10-verified).
// Decision-bit-identical optimizations vs R10:
//  * warm pass streams the batch's n rows once -> pop loads L2-hot
//  * pop-0 row (always row `cur`) prefetched during the previous phase
//  * float4 loads: 16 slots, j = s*256 + lane*4 + e (monotone in (s,e) ->
//    same lowest-j tie-breaks); values & op order identical
//  * row4col lookup via c4r ballot (replaces 15-deep register select)
//  * SC/validity via B[idx] in {0,+INF}: r+(+0.0) is exact, +INF blocks
__global__ __launch_bounds__(64, 1) void lsa_kernel(const float* __restrict__ cost,
                                                    const int* __restrict__ nvalid,
                                                    const int* __restrict__ valid_idx,
                                                    const int* __restrict__ glabels,
                                                    const float* __restrict__ lse_g,
                                                    const float* __restrict__ pboxes,
                                                    const float* __restrict__ gboxes,
                                                    const float* __restrict__ logits,
                                                    double* __restrict__ acc,
                                                    float* __restrict__ dummy) {
    int b = blockIdx.x;
    int n = nvalid[b];
    int lane = threadIdx.x;
    const float* cbase = cost + (size_t)b * GG * QQ;

    // warm pass: pull the batch's cost rows into (XCD) L2
    float wsum = 0.f;
    {
        const float4* p4 = (const float4*)cbase;
        int tot = n * (QQ / 4);
        for (int i = lane; i < tot; i += 64) {
            float4 x = p4[i];
            wsum += x.x + x.y + x.z + x.w;
        }
    }
    if (wsum == -1.2345e30f) dummy[lane] = wsum;  // never true; keeps loads live

    float v[16], sh[16], B[16];
    int path_r[16];
    float u_r[2], srv_r[2];
    int c4r_r[2];
    bool s3ok = lane < 33;  // slot-3 columns j = 768 + lane*4 + e valid iff lane <= 32

#pragma unroll
    for (int i = 0; i < 16; ++i) v[i] = 0.f;
#pragma unroll
    for (int s = 0; s < 2; ++s) { u_r[s] = 0.f; c4r_r[s] = -1; srv_r[s] = 0.f; }

    // prefetch row 0 for phase 0's pop 0
    float4 pv4[4];
    {
        const float4* r4 = (const float4*)cbase;
#pragma unroll
        for (int s = 0; s < 4; ++s) pv4[s] = r4[s * 64 + lane];
    }

    for (int cur = 0; cur < n; ++cur) {
        unsigned sc = 0, srm = 0;
#pragma unroll
        for (int i = 0; i < 16; ++i) {
            sh[i] = INFINITY;
            B[i] = (i < 12 || s3ok) ? 0.f : INFINITY;
        }
        int i2 = cur;
        float minv = 0.f;
        int sink = -1;
        bool first = true;
        for (int pop = 0; pop < QQ && sink < 0; ++pop) {
            float uv = (i2 >> 6) ? u_r[1] : u_r[0];
            float ui = __uint_as_float(
                (unsigned)__builtin_amdgcn_readlane((int)__float_as_uint(uv), i2 & 63));
            float4 cv4[4];
            if (first) {
#pragma unroll
                for (int s = 0; s < 4; ++s) cv4[s] = pv4[s];
                // issue next phase's pop-0 prefetch (row cur+1); latency hides
                // behind the rest of this phase
                int nxt = (cur + 1 < n) ? cur + 1 : cur;
                const float4* r4n = (const float4*)(cbase + (size_t)nxt * QQ);
#pragma unroll
                for (int s = 0; s < 4; ++s) pv4[s] = r4n[s * 64 + lane];
            } else {
                const float4* r4 = (const float4*)(cbase + (size_t)i2 * QQ);
#pragma unroll
                for (int s = 0; s < 4; ++s) cv4[s] = r4[s * 64 + lane];
            }
            first = false;
            float base = minv - ui;
            float lmin = INFINITY;
            int lidx = 0;
#define SLOT(idx, elem)                                                         \
            {                                                                   \
                float r = base + (elem) - v[idx] + B[idx];                      \
                if (r < sh[idx]) { sh[idx] = r; path_r[idx] = i2; }             \
                float m = sh[idx] + B[idx];                                     \
                if (m < lmin) { lmin = m; lidx = idx; }                         \
            }
            SLOT(0, cv4[0].x)  SLOT(1, cv4[0].y)  SLOT(2, cv4[0].z)  SLOT(3, cv4[0].w)
            SLOT(4, cv4[1].x)  SLOT(5, cv4[1].y)  SLOT(6, cv4[1].z)  SLOT(7, cv4[1].w)
            SLOT(8, cv4[2].x)  SLOT(9, cv4[2].y)  SLOT(10, cv4[2].z) SLOT(11, cv4[2].w)
            SLOT(12, cv4[3].x) SLOT(13, cv4[3].y) SLOT(14, cv4[3].z) SLOT(15, cv4[3].w)
#undef SLOT
            float gmin = wave_min_f32(lmin);
            unsigned cand = (lmin == gmin)
                                ? (unsigned)(((lidx >> 2) << 8) + (lane << 2) + (lidx & 3))
                                : 0xFFFFFFFFu;
            int lj = (int)wave_min_u32(cand);  // lowest column among ties
            minv = gmin;
            int oslot = ((lj >> 8) << 2) | (lj & 3);
            if (lane == ((lj >> 2) & 63)) {
                sc |= (1u << oslot);
#pragma unroll
                for (int i = 0; i < 16; ++i)
                    if (i == oslot) B[i] = INFINITY;
            }
            // row4col[lj] via ballot over col4row (each col matched to <=1 row)
            unsigned long long b0 = __ballot(c4r_r[0] == lj);
            unsigned long long b1 = __ballot(c4r_r[1] == lj);
            if ((b0 | b1) == 0ULL) {
                sink = lj;
            } else {
                i2 = b0 ? (int)__builtin_ctzll(b0) : 64 + (int)__builtin_ctzll(b1);
                if (lane == (i2 & 63)) {
#pragma unroll
                    for (int s = 0; s < 2; ++s)
                        if (s == (i2 >> 6)) { srm |= (1u << s); srv_r[s] = minv; }
                }
            }
        }
        if (sink < 0) break;  // safety (cannot happen)
        // dual updates (reference order: before augmentation)
        if (lane == (cur & 63)) {
#pragma unroll
            for (int s = 0; s < 2; ++s)
                if (s == (cur >> 6)) u_r[s] += minv;
        }
#pragma unroll
        for (int s = 0; s < 2; ++s)
            if ((srm >> s) & 1u) u_r[s] += minv - srv_r[s];
#pragma unroll
        for (int i = 0; i < 16; ++i)
            if ((sc >> i) & 1u) v[i] -= (minv - sh[i]);
        // augment (wave-cooperative, uniform walk; row4col not maintained)
        int j = sink;
        while (true) {
            int plane = (j >> 2) & 63, pslot = ((j >> 8) << 2) | (j & 3);
            int pv = 0;
#pragma unroll
            for (int i = 0; i < 16; ++i)
                if (i == pslot) pv = path_r[i];
            int pi = __builtin_amdgcn_readlane(pv, plane);
            int cslot = pi >> 6, clane = pi & 63;
            int cvv = 0;
#pragma unroll
            for (int s = 0; s < 2; ++s)
                if (s == cslot) cvv = c4r_r[s];
            int nj = __builtin_amdgcn_readlane(cvv, clane);
            if (lane == clane) {
#pragma unroll
                for (int s = 0; s < 2; ++s)
                    if (s == cslot) c4r_r[s] = j;
            }
            j = nj;
            if (pi == cur) break;
        }
    }

    // ---- fused matched-pair losses ----
    double ce = 0.0, dl1 = 0.0, dgi = 0.0;
#pragma unroll
    for (int s = 0; s < 2; ++s) {
        int r = s * 64 + lane;
        int q = c4r_r[s];
        if (r < n && q >= 0 && q < QQ) {
            int g = valid_idx[b * GG + r];
            int label = glabels[b * GG + g];
            if (label < 0 || label >= CC) label = 0;
            size_t ro = ((size_t)b * QQ + q) * CC;
            float ls = lse_g[b * QQ + q];
            float nll_lab = ls - logits[ro + label];
            float nll_no = ls - logits[ro + NCL];
            ce += 0.1 * (double)nll_lab - (double)nll_no;
            float4 pb = ((const float4*)pboxes)[b * QQ + q];
            float4 gb = ((const float4*)gboxes)[b * GG + g];
            float l1 = fabsf(pb.x - gb.x) + fabsf(pb.y - gb.y) + fabsf(pb.z - gb.z) + fabsf(pb.w - gb.w);
            float px0 = pb.x - 0.5f * pb.z, py0 = pb.y - 0.5f * pb.w;
            float px1 = pb.x + 0.5f * pb.z, py1 = pb.y + 0.5f * pb.w;
            float gx0 = gb.x - 0.5f * gb.z, gy0 = gb.y - 0.5f * gb.w;
            float gx1 = gb.x + 0.5f * gb.z, gy1 = gb.y + 0.5f * gb.w;
            float parea = (px1 - px0) * (py1 - py0);
            float garea = (gx1 - gx0) * (gy1 - gy0);
            float ltx = fmaxf(px0, gx0), lty = fmaxf(py0, gy0);
            float rbx = fminf(px1, gx1), rby = fminf(py1, gy1);
            float iw = fmaxf(rbx - ltx, 0.f), ih = fmaxf(rby - lty, 0.f);
            float inter = iw * ih;
            float uni = parea + garea - inter;
            float iou = inter / uni;
            float cx0 = fminf(px0, gx0), cy0 = fminf(py0, gy0);
            float cx1 = fmaxf(px1, gx1), cy1 = fmaxf(py1, gy1);
            float cw = fmaxf(cx1 - cx0, 0.f), ch = fmaxf(cy1 - cy0, 0.f);
            float ac = cw * ch;
            float giou = iou - (ac - uni) / ac;
            dl1 += (double)l1;
            dgi += 1.0 - (double)giou;
        }
    }
#pragma unroll
    for (int off = 32; off; off >>= 1) {
        ce += __shfl_down(ce, off);
        dl1 += __shfl_down(dl1, off);
        dgi += __shfl_down(dgi, off);
    }
    if (lane == 0) {
        atomicAdd(&acc[1], ce);
        atomicAdd(&acc[2], dl1);
        atomicAdd(&acc[3], dgi);
    }
}

// One wave: reduce nvalid -> M, compute the three losses.
__global__ __launch_bounds__(64) void final_kernel(const int* __restrict__ nvalid,
                                                   const double* __restrict__ acc,
                                                   float* __restrict__ out) {
    int lane = threadIdx.x;
    int m = nvalid[lane] + nvalid[64 + lane];  // BB = 128
#pragma unroll
    for (int off = 32; off; off >>= 1) m += __shfl_down(m, off);
    if (lane == 0) {
        double M = (double)m;
        double sum_w = (double)(BB * QQ) - 0.9 * M;
        out[0] = (float)((acc[0] + acc[1]) / sum_w);
        out[1] = (float)(acc[2] / (4.0 * M));
        out[2] = (float)(acc[3] / M);
    }
}

extern "C" void kernel_launch(void* const* d_in, const int* in_sizes, int n_in,
                              void* d_out, int out_size, void* d_ws, size_t ws_size,
                              hipStream_t stream) {
    const float* logits = (const float*)d_in[0];
    const float* pboxes = (const float*)d_in[1];
    const int* glabels = (const int*)d_in[2];
    const float* gboxes = (const float*)d_in[3];
    float* out = (float*)d_out;

    char* ws = (char*)d_ws;
    float* cost = (float*)(ws + COST_OFF);
    float* lse = (float*)(ws + LSE_OFF);
    int* vidx = (int*)(ws + VIDX_OFF);
    int* nval = (int*)(ws + NV_OFF);
    float* dummy = (float*)(ws + DUM_OFF);
    double* acc = (double*)(ws + ACC_OFF);

    hipMemsetAsync(acc, 0, 4 * sizeof(double), stream);
    front_kernel<<<BB * 4, 256, 0, stream>>>(logits, pboxes, gboxes, glabels, lse, vidx, nval, cost,
                                             acc);
    lsa_kernel<<<BB, 64, 0, stream>>>(cost, nval, vidx, glabels, lse, pboxes, gboxes, logits, acc,
                                      dummy);
    final_kernel<<<1, 64, 0, stream>>>(nval, acc, out);
}

// Round 12
// 246.458 us; speedup vs baseline: 1.2481x; 1.2481x over previous
//
#include <hip/hip_runtime.h>
#include <math.h>

#define BB 128
#define QQ 900
#define GG 80
#define CC 92
#define NCL 91
#define NSLOT 15  // ceil(QQ/64)

// ---------------- ws layout (bytes) ----------------
#define COST_OFF 0            // float[BB*GG*QQ]  36,864,000
#define LSE_OFF  36864000     // float[BB*QQ]
#define VIDX_OFF 37324800     // int[BB*GG]
#define NV_OFF   37365760     // int[BB]
#define FPART_OFF 37366272    // double[512]  front CE-base partials (per block)
#define MPART_OFF 37370368    // double[BB*3] lsa matched partials [ce,l1,giou]

#define FRONT_LDS_BYTES (225 * 93 * 4)  // 83,700 (stride 93: conflict-free lane reads)

// Fused front kernel v3: FOUR blocks per batch (grid BB*4, 256 thr, 225 q each).
// The block's contiguous 225x92-float logits slab is staged into dynamic LDS
// (coalesced copy in; padded stride 93 so lane-strided reads spread over all
// 32 banks). lse + the per-k label gathers then read LDS -- removing the
// fully-divergent global reads (64 lines/instr) of R10/R11. CE-base partial
// goes to fpart[block] (no atomics). All fp32 expression trees are IDENTICAL
// to R10/R11 -> cost/lse bits unchanged -> lsa traversal unchanged.
__global__ __launch_bounds__(256) void front_kernel(const float* __restrict__ logits,
                                                    const float* __restrict__ pboxes,
                                                    const float* __restrict__ gboxes,
                                                    const int* __restrict__ glabels,
                                                    float* __restrict__ lse_g,
                                                    int* __restrict__ valid_idx,
                                                    int* __restrict__ nvalid,
                                                    float* __restrict__ cost,
                                                    double* __restrict__ fpart) {
    extern __shared__ float sL[];  // [225][93]
    __shared__ int svidx[GG];
    __shared__ int s_n;
    __shared__ int slab[GG];
    __shared__ float sgx0[GG], sgy0[GG], sgx1[GG], sgy1[GG], sgar[GG];
    __shared__ float sgcx[GG], sgcy[GG], sgcz[GG], sgcw[GG];
    __shared__ double sce[4];
    int blk = blockIdx.x;
    int b = blk >> 2;
    int part = blk & 3;
    int tid = threadIdx.x;
    if (tid < 64) {
        int lane = tid;
        bool v0 = glabels[b * GG + lane] < NCL;
        bool v1 = (lane < GG - 64) ? (glabels[b * GG + 64 + lane] < NCL) : false;
        unsigned long long m0 = __ballot(v0);
        unsigned long long m1 = __ballot(v1);
        int c0 = __popcll(m0);
        unsigned long long lower = lane ? (~0ULL >> (64 - lane)) : 0ULL;
        if (v0) { int p = __popcll(m0 & lower); svidx[p] = lane; valid_idx[b * GG + p] = lane; }
        if (v1) { int p = c0 + __popcll(m1 & lower); svidx[p] = 64 + lane; valid_idx[b * GG + p] = 64 + lane; }
        if (lane == 0) { s_n = c0 + __popcll(m1); nvalid[b] = s_n; }
    }
    __syncthreads();
    int n = s_n;

    // stage logits slab -> LDS (coalesced dword reads; padded stride 93)
    {
        const float* src = logits + ((size_t)(b * QQ) + part * 225) * CC;
        for (int i = tid; i < 225 * CC; i += 256) {
            int ql = i / CC;
            int c = i - ql * CC;
            sL[ql * 93 + c] = src[i];
        }
    }
    // gt staging
    for (int k = tid; k < n; k += 256) {
        int g = svidx[k];
        slab[k] = glabels[b * GG + g];
        float4 gb = ((const float4*)gboxes)[b * GG + g];
        sgcx[k] = gb.x; sgcy[k] = gb.y; sgcz[k] = gb.z; sgcw[k] = gb.w;
        float gx0 = gb.x - 0.5f * gb.z, gy0 = gb.y - 0.5f * gb.w;
        float gx1 = gb.x + 0.5f * gb.z, gy1 = gb.y + 0.5f * gb.w;
        sgx0[k] = gx0; sgy0[k] = gy0; sgx1[k] = gx1; sgy1[k] = gy1;
        sgar[k] = (gx1 - gx0) * (gy1 - gy0);
    }
    __syncthreads();

    int q = part * 225 + tid;
    bool qok = tid < 225;
    const float* row = sL + tid * 93;

    // lse (identical expression tree to R10/R11; values from LDS are identical)
    double local = 0.0;
    float lse_q = 0.f;
    if (qok) {
        float mx = -INFINITY;
        for (int c = 0; c < 23; ++c) {
            float x0 = row[4 * c], x1 = row[4 * c + 1], x2 = row[4 * c + 2], x3 = row[4 * c + 3];
            mx = fmaxf(mx, fmaxf(fmaxf(x0, x1), fmaxf(x2, x3)));
        }
        float ssum = 0.f;
        float e91 = 0.f;
        for (int c = 0; c < 23; ++c) {
            float x0 = row[4 * c], x1 = row[4 * c + 1], x2 = row[4 * c + 2], x3 = row[4 * c + 3];
            ssum += expf(x0 - mx) + expf(x1 - mx) + expf(x2 - mx) + expf(x3 - mx);
            if (c == 22) e91 = x3;  // element 91
        }
        lse_q = mx + logf(ssum);
        lse_g[b * QQ + q] = lse_q;
        local = (double)lse_q - (double)e91;
    }
#pragma unroll
    for (int off = 32; off; off >>= 1) local += __shfl_down(local, off);
    if ((tid & 63) == 0) sce[tid >> 6] = local;

    // cost (identical fp32 op order; gather from LDS)
    if (qok) {
        float4 pb = ((const float4*)pboxes)[b * QQ + q];
        float px0 = pb.x - 0.5f * pb.z, py0 = pb.y - 0.5f * pb.w;
        float px1 = pb.x + 0.5f * pb.z, py1 = pb.y + 0.5f * pb.w;
        float parea = (px1 - px0) * (py1 - py0);
        for (int k = 0; k < n; ++k) {
            float l1 = fabsf(pb.x - sgcx[k]) + fabsf(pb.y - sgcy[k]) +
                       fabsf(pb.z - sgcz[k]) + fabsf(pb.w - sgcw[k]);
            float ltx = fmaxf(px0, sgx0[k]), lty = fmaxf(py0, sgy0[k]);
            float rbx = fminf(px1, sgx1[k]), rby = fminf(py1, sgy1[k]);
            float iw = fmaxf(rbx - ltx, 0.f), ih = fmaxf(rby - lty, 0.f);
            float inter = iw * ih;
            float uni = parea + sgar[k] - inter;
            float iou = inter / uni;
            float cx0 = fminf(px0, sgx0[k]), cy0 = fminf(py0, sgy0[k]);
            float cx1 = fmaxf(px1, sgx1[k]), cy1 = fmaxf(py1, sgy1[k]);
            float cw = fmaxf(cx1 - cx0, 0.f), ch = fmaxf(cy1 - cy0, 0.f);
            float ac = cw * ch;
            float giou = iou - (ac - uni) / ac;
            float cls = lse_q - row[slab[k]];
            cost[((size_t)(b * GG + k)) * QQ + q] = 5.f * l1 + cls - 2.f * giou;
        }
    }
    __syncthreads();
    if (tid == 0) fpart[blk] = sce[0] + sce[1] + sce[2] + sce[3];
}

// Wave64 min-reduce via DPP (row_shr 1/2/4/8 + bcast15/31), result in lane 63.
__device__ __forceinline__ unsigned wave_min_u32(unsigned x) {
    unsigned t;
    t = (unsigned)__builtin_amdgcn_update_dpp((int)x, (int)x, 0x111, 0xF, 0xF, false); x = x < t ? x : t;
    t = (unsigned)__builtin_amdgcn_update_dpp((int)x, (int)x, 0x112, 0xF, 0xF, false); x = x < t ? x : t;
    t = (unsigned)__builtin_amdgcn_update_dpp((int)x, (int)x, 0x114, 0xF, 0xF, false); x = x < t ? x : t;
    t = (unsigned)__builtin_amdgcn_update_dpp((int)x, (int)x, 0x118, 0xF, 0xF, false); x = x < t ? x : t;
    t = (unsigned)__builtin_amdgcn_update_dpp((int)x, (int)x, 0x142, 0xF, 0xF, false); x = x < t ? x : t;
    t = (unsigned)__builtin_amdgcn_update_dpp((int)x, (int)x, 0x143, 0xF, 0xF, false); x = x < t ? x : t;
    return (unsigned)__builtin_amdgcn_readlane((int)x, 63);
}
// fp32 variant (fminf; values here are never NaN).
__device__ __forceinline__ float wave_min_f32(float x) {
    float t;
#define MSTEP(ctrl)                                                                               \
    t = __uint_as_float((unsigned)__builtin_amdgcn_update_dpp(                                    \
        (int)__float_as_uint(x), (int)__float_as_uint(x), ctrl, 0xF, 0xF, false));                \
    x = fminf(x, t);
    MSTEP(0x111) MSTEP(0x112) MSTEP(0x114) MSTEP(0x118) MSTEP(0x142) MSTEP(0x143)
#undef MSTEP
    return __uint_as_float((unsigned)__builtin_amdgcn_readlane((int)__float_as_uint(x), 63));
}

// One exact SAP phase (scipy semantics) for row `cur`.
// Bit-for-bit the R10-proven dataflow; global fp32 cost rows.
__device__ __forceinline__ bool sap_phase(int cur, int lane, const float* cbase,
                                          unsigned valid_mask, float (&v)[NSLOT],
                                          int (&r4c_r)[NSLOT], float (&u_r)[2],
                                          int (&c4r_r)[2]) {
    float sh[NSLOT];
    int path_r[NSLOT];
    float srv_r[2] = {0.f, 0.f};
    unsigned sc = 0, srm = 0;
#pragma unroll
    for (int s = 0; s < NSLOT; ++s) sh[s] = INFINITY;
    int i2 = cur;
    float minv = 0.f;
    int sink = -1;
    for (int pop = 0; pop < QQ && sink < 0; ++pop) {
        float uv = (i2 >> 6) ? u_r[1] : u_r[0];
        float ui = __uint_as_float(
            (unsigned)__builtin_amdgcn_readlane((int)__float_as_uint(uv), i2 & 63));
        const float* crow = cbase + (size_t)i2 * QQ;
        float cv[NSLOT];
#pragma unroll
        for (int s = 0; s < NSLOT; ++s) {
            int j = s * 64 + lane;
            cv[s] = (j < QQ) ? crow[j] : 0.f;
        }
        float base = minv - ui;
        unsigned act = valid_mask & ~sc;
        float lmin = INFINITY;
        int lslot = 0;
#pragma unroll
        for (int s = 0; s < NSLOT; ++s) {
            if ((act >> s) & 1u) {
                float r = base + cv[s] - v[s];
                if (r < sh[s]) { sh[s] = r; path_r[s] = i2; }
                if (sh[s] < lmin) { lmin = sh[s]; lslot = s; }
            }
        }
        float gmin = wave_min_f32(lmin);
        unsigned cand = (lmin == gmin) ? (unsigned)(lslot * 64 + lane) : 0xFFFFFFFFu;
        int lj = (int)wave_min_u32(cand);  // lowest column among ties
        minv = gmin;
        if (lane == (lj & 63)) sc |= (1u << (lj >> 6));
        int rv = -1;
#pragma unroll
        for (int s = 0; s < NSLOT; ++s)
            if (s == (lj >> 6)) rv = r4c_r[s];
        int r4c = __builtin_amdgcn_readlane(rv, lj & 63);
        if (r4c == -1) {
            sink = lj;
        } else {
            i2 = r4c;
            if (lane == (i2 & 63)) {
#pragma unroll
                for (int s = 0; s < 2; ++s)
                    if (s == (i2 >> 6)) { srm |= (1u << s); srv_r[s] = minv; }
            }
        }
    }
    if (sink < 0) return false;
    // dual updates (reference order: before augmentation)
    if (lane == (cur & 63)) {
#pragma unroll
        for (int s = 0; s < 2; ++s)
            if (s == (cur >> 6)) u_r[s] += minv;
    }
#pragma unroll
    for (int s = 0; s < 2; ++s)
        if ((srm >> s) & 1u) u_r[s] += minv - srv_r[s];
#pragma unroll
    for (int s = 0; s < NSLOT; ++s)
        if ((sc >> s) & 1u) v[s] -= (minv - sh[s]);
    // augment (wave-cooperative, uniform walk)
    int j = sink;
    while (true) {
        int pslot = j >> 6, plane = j & 63;
        int pv = 0;
#pragma unroll
        for (int s = 0; s < NSLOT; ++s)
            if (s == pslot) pv = path_r[s];
        int pi = __builtin_amdgcn_readlane(pv, plane);
        if (lane == plane) {
#pragma unroll
            for (int s = 0; s < NSLOT; ++s)
                if (s == pslot) r4c_r[s] = pi;
        }
        int cslot = pi >> 6, clane = pi & 63;
        int cvv = 0;
#pragma unroll
        for (int s = 0; s < 2; ++s)
            if (s == cslot) cvv = c4r_r[s];
        int nj = __builtin_amdgcn_readlane(cvv, clane);
        if (lane == clane) {
#pragma unroll
            for (int s = 0; s < 2; ++s)
                if (s == cslot) c4r_r[s] = j;
        }
        j = nj;
        if (pi == cur) break;
    }
    return true;
}

// R10-proven exact LSA: v=0 init, sequential SAP rows 0..n-1 (scipy traversal;
// the matching is traversal-determined -- R7/R8/R9 colmin variants all failed
// identically, R10 passed). One 64-lane wave per batch, all state in
// registers. Only change vs R10: tail writes per-batch partials (no atomics).
__global__ __launch_bounds__(64, 1) void lsa_kernel(const float* __restrict__ cost,
                                                    const int* __restrict__ nvalid,
                                                    const int* __restrict__ valid_idx,
                                                    const int* __restrict__ glabels,
                                                    const float* __restrict__ lse_g,
                                                    const float* __restrict__ pboxes,
                                                    const float* __restrict__ gboxes,
                                                    const float* __restrict__ logits,
                                                    double* __restrict__ mpart) {
    int b = blockIdx.x;
    int n = nvalid[b];
    const float* cbase = cost + (size_t)b * GG * QQ;
    int lane = threadIdx.x;

    float v[NSLOT];
    int r4c_r[NSLOT];
    float u_r[2];
    int c4r_r[2];
    unsigned valid_mask = 0x3FFFu | ((lane < QQ - 14 * 64) ? 0x4000u : 0u);
#pragma unroll
    for (int s = 0; s < NSLOT; ++s) { v[s] = 0.f; r4c_r[s] = -1; }
#pragma unroll
    for (int s = 0; s < 2; ++s) { u_r[s] = 0.f; c4r_r[s] = -1; }

    for (int cur = 0; cur < n; ++cur)
        sap_phase(cur, lane, cbase, valid_mask, v, r4c_r, u_r, c4r_r);

    // ---- fused matched-pair losses ----
    double ce = 0.0, dl1 = 0.0, dgi = 0.0;
#pragma unroll
    for (int s = 0; s < 2; ++s) {
        int r = s * 64 + lane;
        int q = c4r_r[s];
        if (r < n && q >= 0 && q < QQ) {
            int g = valid_idx[b * GG + r];
            int label = glabels[b * GG + g];
            if (label < 0 || label >= CC) label = 0;
            size_t ro = ((size_t)b * QQ + q) * CC;
            float ls = lse_g[b * QQ + q];
            float nll_lab = ls - logits[ro + label];
            float nll_no = ls - logits[ro + NCL];
            ce += 0.1 * (double)nll_lab - (double)nll_no;
            float4 pb = ((const float4*)pboxes)[b * QQ + q];
            float4 gb = ((const float4*)gboxes)[b * GG + g];
            float l1 = fabsf(pb.x - gb.x) + fabsf(pb.y - gb.y) + fabsf(pb.z - gb.z) + fabsf(pb.w - gb.w);
            float px0 = pb.x - 0.5f * pb.z, py0 = pb.y - 0.5f * pb.w;
            float px1 = pb.x + 0.5f * pb.z, py1 = pb.y + 0.5f * pb.w;
            float gx0 = gb.x - 0.5f * gb.z, gy0 = gb.y - 0.5f * gb.w;
            float gx1 = gb.x + 0.5f * gb.z, gy1 = gb.y + 0.5f * gb.w;
            float parea = (px1 - px0) * (py1 - py0);
            float garea = (gx1 - gx0) * (gy1 - gy0);
            float ltx = fmaxf(px0, gx0), lty = fmaxf(py0, gy0);
            float rbx = fminf(px1, gx1), rby = fminf(py1, gy1);
            float iw = fmaxf(rbx - ltx, 0.f), ih = fmaxf(rby - lty, 0.f);
            float inter = iw * ih;
            float uni = parea + garea - inter;
            float iou = inter / uni;
            float cx0 = fminf(px0, gx0), cy0 = fminf(py0, gy0);
            float cx1 = fmaxf(px1, gx1), cy1 = fmaxf(py1, gy1);
            float cw = fmaxf(cx1 - cx0, 0.f), ch = fmaxf(cy1 - cy0, 0.f);
            float ac = cw * ch;
            float giou = iou - (ac - uni) / ac;
            dl1 += (double)l1;
            dgi += 1.0 - (double)giou;
        }
    }
#pragma unroll
    for (int off = 32; off; off >>= 1) {
        ce += __shfl_down(ce, off);
        dl1 += __shfl_down(dl1, off);
        dgi += __shfl_down(dgi, off);
    }
    if (lane == 0) {
        mpart[b * 3 + 0] = ce;
        mpart[b * 3 + 1] = dl1;
        mpart[b * 3 + 2] = dgi;
    }
}

// One wave: sum partials + nvalid -> the three losses (no atomics anywhere).
__global__ __launch_bounds__(64) void final_kernel(const int* __restrict__ nvalid,
                                                   const double* __restrict__ fpart,
                                                   const double* __restrict__ mpart,
                                                   float* __restrict__ out) {
    int lane = threadIdx.x;
    int m = nvalid[lane] + nvalid[64 + lane];  // BB = 128
    double fb = 0.0;
    for (int i = lane; i < BB * 4; i += 64) fb += fpart[i];
    double ce = 0.0, dl1 = 0.0, dgi = 0.0;
#pragma unroll
    for (int s = 0; s < 2; ++s) {
        int bb = s * 64 + lane;
        ce += mpart[bb * 3 + 0];
        dl1 += mpart[bb * 3 + 1];
        dgi += mpart[bb * 3 + 2];
    }
#pragma unroll
    for (int off = 32; off; off >>= 1) {
        m += __shfl_down(m, off);
        fb += __shfl_down(fb, off);
        ce += __shfl_down(ce, off);
        dl1 += __shfl_down(dl1, off);
        dgi += __shfl_down(dgi, off);
    }
    if (lane == 0) {
        double M = (double)m;
        double sum_w = (double)(BB * QQ) - 0.9 * M;
        out[0] = (float)((fb + ce) / sum_w);
        out[1] = (float)(dl1 / (4.0 * M));
        out[2] = (float)(dgi / M);
    }
}

extern "C" void kernel_launch(void* const* d_in, const int* in_sizes, int n_in,
                              void* d_out, int out_size, void* d_ws, size_t ws_size,
                              hipStream_t stream) {
    const float* logits = (const float*)d_in[0];
    const float* pboxes = (const float*)d_in[1];
    const int* glabels = (const int*)d_in[2];
    const float* gboxes = (const float*)d_in[3];
    float* out = (float*)d_out;

    char* ws = (char*)d_ws;
    float* cost = (float*)(ws + COST_OFF);
    float* lse = (float*)(ws + LSE_OFF);
    int* vidx = (int*)(ws + VIDX_OFF);
    int* nval = (int*)(ws + NV_OFF);
    double* fpart = (double*)(ws + FPART_OFF);
    double* mpart = (double*)(ws + MPART_OFF);

    (void)hipFuncSetAttribute((const void*)front_kernel,
                              hipFuncAttributeMaxDynamicSharedMemorySize, FRONT_LDS_BYTES);

    front_kernel<<<BB * 4, 256, FRONT_LDS_BYTES, stream>>>(logits, pboxes, gboxes, glabels, lse,
                                                           vidx, nval, cost, fpart);
    lsa_kernel<<<BB, 64, 0, stream>>>(cost, nval, vidx, glabels, lse, pboxes, gboxes, logits, mpart);
    final_kernel<<<1, 64, 0, stream>>>(nval, fpart, mpart, out);
}